// Round 1
// baseline (139.082 us; speedup 1.0000x reference)
//
#include <hip/hip_runtime.h>

// LSTM (B=131072, T=24, input=3, H=32) + Linear(32,16)+ReLU+Linear(16,1)
//
// Formulation: per timestep compute gates^T = Whh_bf16 * h^T + Wib_bf16 * [x;1]^T
// with v_mfma_f32_16x16x32_bf16. A-operand (weights) is wave-uniform and lives
// permanently in VGPR fragments. Each wave owns 16 batch rows. h round-trips
// through a per-wave private 1KB LDS tile in bf16; c-state stays f32 in regs.
// Gate order (PyTorch): rows [0,32)=i, [32,64)=f, [64,96)=g, [96,128)=o.

typedef short bf16x8 __attribute__((ext_vector_type(8)));
typedef float f32x4 __attribute__((ext_vector_type(4)));

#define L2E 1.4426950408889634f

__device__ __forceinline__ unsigned f2bf(float f) {
    unsigned u = __float_as_uint(f);
    return (u + 0x7FFFu + ((u >> 16) & 1u)) >> 16;   // RNE to bf16 (no NaNs here)
}
__device__ __forceinline__ float bf2f(int s) {
    return __uint_as_float(((unsigned)(s & 0xFFFF)) << 16);
}
__device__ __forceinline__ float fexp2(float v) { return __builtin_amdgcn_exp2f(v); }
__device__ __forceinline__ float frcp(float v)  { return __builtin_amdgcn_rcpf(v); }

__global__ __launch_bounds__(256)
void lstm_fused(const float* __restrict__ x,
                const float* __restrict__ w_ih,
                const float* __restrict__ w_hh,
                const float* __restrict__ b_ih,
                const float* __restrict__ b_hh,
                const float* __restrict__ w1,
                const float* __restrict__ b1,
                const float* __restrict__ w2,
                const float* __restrict__ b2,
                float* __restrict__ out)
{
    __shared__ int2  xq[24 * 64];   // [t][n] packed bf16 {x0,x1 | x2,1.0}  (12 KB)
    __shared__ int4  hbuf[4 * 64];  // per-wave h tile: [wv][c(16)][k(32)] bf16 (4 KB)
    __shared__ float w1s[512];
    __shared__ float b1s[16];
    __shared__ float w2s[16];
    __shared__ float b2s;

    const int tid  = threadIdx.x;
    const int lane = tid & 63;
    const int wv   = tid >> 6;      // wave id 0..3
    const int c    = lane & 15;     // batch column within wave tile
    const int g    = lane >> 4;     // k-group 0..3
    const int blockBase = blockIdx.x * 64;

    // ---- stage head weights to LDS ----
    for (int i = tid; i < 512; i += 256) w1s[i] = w1[i];
    if (tid < 16) { b1s[tid] = b1[tid]; w2s[tid] = w2[tid]; }
    if (tid == 16) b2s = b2[0];

    // ---- stage x for this block's 64 rows: pack (x0,x1,x2,1.0) as bf16 ----
    for (int it = 0; it < 6; ++it) {
        int p = tid + it * 256;          // 0..1535 = 64 rows * 24 steps
        int n = p / 24;
        int t = p - n * 24;
        const float* xp = x + ((blockBase + n) * 24 + t) * 3;
        unsigned lo = f2bf(xp[0]) | (f2bf(xp[1]) << 16);
        unsigned hi = f2bf(xp[2]) | (0x3F80u << 16);   // 1.0bf16 multiplies bias col
        xq[t * 64 + n] = make_int2((int)lo, (int)hi);
    }

    // ---- zero h tile (h0 = 0) ----
    hbuf[wv * 64 + lane] = make_int4(0, 0, 0, 0);

    // ---- preload weight A-fragments (wave-uniform, resident in VGPRs) ----
    // A layout (16x16x32 bf16): row = lane&15, k = 8*(lane>>4) + e
    bf16x8 whh[8], wib[8];
#pragma unroll
    for (int m = 0; m < 8; ++m) {
        const int row = 16 * m + c;                 // gate index
        const float* wr = w_hh + row * 32 + g * 8;
        bf16x8 a;
#pragma unroll
        for (int e = 0; e < 8; ++e) a[e] = (short)f2bf(wr[e]);
        whh[m] = a;
        bf16x8 bb = {0, 0, 0, 0, 0, 0, 0, 0};      // only k=0..3 nonzero (g==0)
        if (g == 0) {
            bb[0] = (short)f2bf(w_ih[row * 3 + 0]);
            bb[1] = (short)f2bf(w_ih[row * 3 + 1]);
            bb[2] = (short)f2bf(w_ih[row * 3 + 2]);
            bb[3] = (short)f2bf(b_ih[row] + b_hh[row]);  // fused bias, hit by 1.0
        }
        wib[m] = bb;
    }

    __syncthreads();

    float cst[8];                                    // c-state: units 16e+4g+j
#pragma unroll
    for (int i = 0; i < 8; ++i) cst[i] = 0.f;

    int2* hb2 = (int2*)hbuf;
    const int hRd     = wv * 64 + c * 4 + g;                    // int4 units
    const int hWrBase = (wv * 1024 + c * 64 + g * 8) >> 3;      // int2 units, +e*4

    for (int t = 0; t < 24; ++t) {
        // B2-frag: [x;1] column for batch c (nonzero only for k-group 0)
        int2 xv = xq[t * 64 + wv * 16 + c];
        int lo = (g == 0) ? xv.x : 0;
        int hi = (g == 0) ? xv.y : 0;
        bf16x8 xf = { (short)(lo & 0xFFFF), (short)((unsigned)lo >> 16),
                      (short)(hi & 0xFFFF), (short)((unsigned)hi >> 16),
                      0, 0, 0, 0 };

        // B-frag: h^T — lane reads h[c][8g..8g+7] (16B, bank-clean)
        int4 hvv = hbuf[hRd];
        union { int4 i; bf16x8 s; } hu; hu.i = hvv;
        bf16x8 hf = hu.s;

#pragma unroll
        for (int e = 0; e < 2; ++e) {   // h-unit halves u in [16e, 16e+16)
            f32x4 ai = {0.f,0.f,0.f,0.f}, af = {0.f,0.f,0.f,0.f},
                  ag = {0.f,0.f,0.f,0.f}, ao = {0.f,0.f,0.f,0.f};
            ai = __builtin_amdgcn_mfma_f32_16x16x32_bf16(whh[0 + e], hf, ai, 0, 0, 0);
            af = __builtin_amdgcn_mfma_f32_16x16x32_bf16(whh[2 + e], hf, af, 0, 0, 0);
            ag = __builtin_amdgcn_mfma_f32_16x16x32_bf16(whh[4 + e], hf, ag, 0, 0, 0);
            ao = __builtin_amdgcn_mfma_f32_16x16x32_bf16(whh[6 + e], hf, ao, 0, 0, 0);
            ai = __builtin_amdgcn_mfma_f32_16x16x32_bf16(wib[0 + e], xf, ai, 0, 0, 0);
            af = __builtin_amdgcn_mfma_f32_16x16x32_bf16(wib[2 + e], xf, af, 0, 0, 0);
            ag = __builtin_amdgcn_mfma_f32_16x16x32_bf16(wib[4 + e], xf, ag, 0, 0, 0);
            ao = __builtin_amdgcn_mfma_f32_16x16x32_bf16(wib[6 + e], xf, ao, 0, 0, 0);

            unsigned hp0 = 0, hp1 = 0;
#pragma unroll
            for (int j = 0; j < 4; ++j) {
                // D layout: row = 4g+j (gate u = 16m+4g+j), col = c (batch)
                float vi = ai[j], vf = af[j], vg = ag[j], vo = ao[j];
                // sig(i)*tanh(g) with one shared rcp
                float ex = fexp2(-vi * L2E);          // e^-i
                float ey = fexp2(2.f * vg * L2E);     // e^(2g)
                float ig = (ey - 1.f) * frcp((1.f + ex) * (1.f + ey));
                float fs = frcp(1.f + fexp2(-vf * L2E));
                float cn = fs * cst[e * 4 + j] + ig;
                cst[e * 4 + j] = cn;
                // sig(o)*tanh(cn) with one shared rcp
                float ew = fexp2(-vo * L2E);
                float ez = fexp2(2.f * cn * L2E);
                float hn = (ez - 1.f) * frcp((1.f + ew) * (1.f + ez));
                unsigned hb = f2bf(hn);
                if (j == 0) hp0 = hb;
                else if (j == 1) hp0 |= hb << 16;
                else if (j == 2) hp1 = hb;
                else hp1 |= hb << 16;
            }
            // write h_new[c][16e+4g .. +3] as 4 bf16 (8B)
            hb2[hWrBase + e * 4] = make_int2((int)hp0, (int)hp1);
        }
        __syncthreads();   // write(t) -> read(t+1) ordering fence
    }

    // ---- head: hid = relu(w1 @ h + b1); logit = w2 @ hid + b2 ----
    float hv[32];
#pragma unroll
    for (int q4 = 0; q4 < 4; ++q4) {
        int4 hq = hbuf[wv * 64 + c * 4 + q4];
        union { int4 i; bf16x8 s; } hu2; hu2.i = hq;
#pragma unroll
        for (int e2 = 0; e2 < 8; ++e2) hv[q4 * 8 + e2] = bf2f(hu2.s[e2]);
    }
    float p = 0.f;
#pragma unroll
    for (int j = 0; j < 4; ++j) {
        int q = 4 * g + j;                     // hid unit, split across k-groups
        float s = b1s[q];
        const float4* wrow = (const float4*)(w1s + q * 32);
#pragma unroll
        for (int k4 = 0; k4 < 8; ++k4) {
            float4 w4 = wrow[k4];
            s += w4.x * hv[k4 * 4 + 0] + w4.y * hv[k4 * 4 + 1]
               + w4.z * hv[k4 * 4 + 2] + w4.w * hv[k4 * 4 + 3];
        }
        s = fmaxf(s, 0.f);
        p += s * w2s[q];
    }
    p += __shfl_xor(p, 16);
    p += __shfl_xor(p, 32);
    if (g == 0) out[blockBase + wv * 16 + c] = p + b2s;
}

extern "C" void kernel_launch(void* const* d_in, const int* in_sizes, int n_in,
                              void* d_out, int out_size, void* d_ws, size_t ws_size,
                              hipStream_t stream) {
    (void)in_sizes; (void)n_in; (void)d_ws; (void)ws_size; (void)out_size;
    const float* x    = (const float*)d_in[0];
    const float* w_ih = (const float*)d_in[1];
    const float* w_hh = (const float*)d_in[2];
    const float* b_ih = (const float*)d_in[3];
    const float* b_hh = (const float*)d_in[4];
    const float* w1   = (const float*)d_in[5];
    const float* b1   = (const float*)d_in[6];
    const float* w2   = (const float*)d_in[7];
    const float* b2   = (const float*)d_in[8];
    float* outp = (float*)d_out;

    dim3 grid(131072 / 64);   // 64 batch rows per block (4 waves x 16)
    dim3 block(256);
    hipLaunchKernelGGL(lstm_fused, grid, block, 0, stream,
                       x, w_ih, w_hh, b_ih, b_hh, w1, b1, w2, b2, outp);
}

// Round 2
// 108.428 us; speedup vs baseline: 1.2827x; 1.2827x over previous
//
#include <hip/hip_runtime.h>

// LSTM (B=131072, T=24, input=3, H=32) + Linear(32,16)+ReLU+Linear(16,1)
//
// Per step: gates^T = Whh * h^T + Wib * [x;1]^T via v_mfma_f32_16x16x32_bf16.
// Weight A-frags live in VGPRs (wave-uniform). Unit->row permutation is chosen
// so each lane's MFMA outputs (D rows 4g+j of halves p=0,1) are exactly the h
// units (8g..8g+7) that the SAME lane feeds into the next step's B-fragment
// (k = 8g+e). => zero cross-lane h traffic, no per-step barrier, no LDS h.
// Weights prescaled by log2e (2*log2e for the g gate) so all exps are exp2.
// c-state stays f32 in registers. Gate order (PyTorch): [i, f, g, o].

typedef short bf16x8 __attribute__((ext_vector_type(8)));
typedef float f32x4 __attribute__((ext_vector_type(4)));

#define L2E 1.4426950408889634f

__device__ __forceinline__ unsigned f2bf(float f) {
    unsigned u = __float_as_uint(f);
    return (u + 0x7FFFu + ((u >> 16) & 1u)) >> 16;   // RNE to bf16
}
__device__ __forceinline__ float fexp2(float v) { return __builtin_amdgcn_exp2f(v); }
__device__ __forceinline__ float frcp(float v)  { return __builtin_amdgcn_rcpf(v); }
__device__ __forceinline__ unsigned cvtpk(float lo, float hi) {
    unsigned r;
    asm("v_cvt_pk_bf16_f32 %0, %1, %2" : "=v"(r) : "v"(lo), "v"(hi));
    return r;
}

__global__ __launch_bounds__(256, 3)
void lstm_fused(const float* __restrict__ x,
                const float* __restrict__ w_ih,
                const float* __restrict__ w_hh,
                const float* __restrict__ b_ih,
                const float* __restrict__ b_hh,
                const float* __restrict__ w1,
                const float* __restrict__ b1,
                const float* __restrict__ w2,
                const float* __restrict__ b2,
                float* __restrict__ out)
{
    __shared__ int2  xq[24 * 64];   // [t][n] packed bf16 {x0,x1 | x2,1.0} (12 KB)
    __shared__ float w1s[512];
    __shared__ float b1s[16];
    __shared__ float w2s[16];
    __shared__ float b2s;

    const int tid  = threadIdx.x;
    const int lane = tid & 63;
    const int wv   = tid >> 6;      // wave id 0..3
    const int c    = lane & 15;     // batch column within wave tile
    const int g    = lane >> 4;     // k-group 0..3
    const int blockBase = blockIdx.x * 64;

    // ---- stage head weights to LDS ----
    for (int i = tid; i < 512; i += 256) w1s[i] = w1[i];
    if (tid < 16) { b1s[tid] = b1[tid]; w2s[tid] = w2[tid]; }
    if (tid == 16) b2s = b2[0];

    // ---- stage x: pack (x0,x1,x2,1.0) as bf16 per (row, t) ----
    for (int it = 0; it < 6; ++it) {
        int p = tid + it * 256;          // 0..1535 = 64 rows * 24 steps
        int n = p / 24;
        int t = p - n * 24;
        const float* xp = x + ((blockBase + n) * 24 + t) * 3;
        unsigned lo = f2bf(xp[0]) | (f2bf(xp[1]) << 16);
        unsigned hi = f2bf(xp[2]) | (0x3F80u << 16);   // 1.0bf16 hits bias col
        xq[t * 64 + n] = make_int2((int)lo, (int)hi);
    }

    // ---- preload weight A-frags (wave-uniform, permuted rows, prescaled) ----
    // MFMA (G,p) row r computes unit(r,p) = 8*(r>>2) + 4p + (r&3).
    // A element e holds A[row=c][k = 8g+e] (k = natural h index).
    bf16x8 whh[8], wib[8];
    const int ubase = 8 * (c >> 2) + (c & 3);
#pragma unroll
    for (int G = 0; G < 4; ++G) {
        const float scale = (G == 2) ? (2.f * L2E) : L2E;
#pragma unroll
        for (int p = 0; p < 2; ++p) {
            const int row = G * 32 + ubase + 4 * p;
            const float* wr = w_hh + row * 32 + g * 8;
            bf16x8 a;
#pragma unroll
            for (int e = 0; e < 8; ++e) a[e] = (short)f2bf(wr[e] * scale);
            whh[G * 2 + p] = a;
            bf16x8 bb = {0, 0, 0, 0, 0, 0, 0, 0};
            if (g == 0) {
                bb[0] = (short)f2bf(w_ih[row * 3 + 0] * scale);
                bb[1] = (short)f2bf(w_ih[row * 3 + 1] * scale);
                bb[2] = (short)f2bf(w_ih[row * 3 + 2] * scale);
                bb[3] = (short)f2bf((b_ih[row] + b_hh[row]) * scale);
            }
            wib[G * 2 + p] = bb;
        }
    }

    __syncthreads();   // xq/w1s staged (only barrier in the kernel)

    float cst[8];                        // c-state for units 8g + (4p+j)
#pragma unroll
    for (int i = 0; i < 8; ++i) cst[i] = 0.f;

    unsigned hd[4] = {0u, 0u, 0u, 0u};   // packed bf16 h[8g..8g+7] (B-frag)
    const int xidx = wv * 16 + c;

#pragma unroll 2
    for (int t = 0; t < 24; ++t) {
        int2 xv = xq[t * 64 + xidx];     // broadcast across g: conflict-free
        union { int4 i4; bf16x8 v; } xu, hu;
        xu.i4 = make_int4((g == 0) ? xv.x : 0, (g == 0) ? xv.y : 0, 0, 0);
        hu.i4 = make_int4((int)hd[0], (int)hd[1], (int)hd[2], (int)hd[3]);
        bf16x8 hf = hu.v, xf = xu.v;

#pragma unroll
        for (int p = 0; p < 2; ++p) {
            f32x4 z = {0.f, 0.f, 0.f, 0.f};
            f32x4 ai = z, af = z, ag = z, ao = z;
            ai = __builtin_amdgcn_mfma_f32_16x16x32_bf16(whh[0 + p], hf, ai, 0, 0, 0);
            af = __builtin_amdgcn_mfma_f32_16x16x32_bf16(whh[2 + p], hf, af, 0, 0, 0);
            ag = __builtin_amdgcn_mfma_f32_16x16x32_bf16(whh[4 + p], hf, ag, 0, 0, 0);
            ao = __builtin_amdgcn_mfma_f32_16x16x32_bf16(whh[6 + p], hf, ao, 0, 0, 0);
            ai = __builtin_amdgcn_mfma_f32_16x16x32_bf16(wib[0 + p], xf, ai, 0, 0, 0);
            af = __builtin_amdgcn_mfma_f32_16x16x32_bf16(wib[2 + p], xf, af, 0, 0, 0);
            ag = __builtin_amdgcn_mfma_f32_16x16x32_bf16(wib[4 + p], xf, ag, 0, 0, 0);
            ao = __builtin_amdgcn_mfma_f32_16x16x32_bf16(wib[6 + p], xf, ao, 0, 0, 0);

            float hn4[4];
#pragma unroll
            for (int j = 0; j < 4; ++j) {
                // lane's value j of half p = preact of unit 8g + 4p + j, batch c
                float vi = ai[j], vf = af[j], vg = ag[j], vo = ao[j];
                float ex = fexp2(-vi);            // e^-i   (prescaled by L2E)
                float ey = fexp2(vg);             // e^2g   (prescaled by 2*L2E)
                float ef = fexp2(-vf);            // e^-f
                float pxy  = (1.f + ex) * (1.f + ey);
                float r1   = frcp(pxy * (1.f + ef));
                float ig   = (ey - 1.f) * (1.f + ef) * r1;   // sig(i)*tanh(g)
                float fs   = pxy * r1;                       // sig(f)
                float cn   = fmaf(fs, cst[4 * p + j], ig);
                cst[4 * p + j] = cn;
                float ew = fexp2(-vo);            // e^-o
                float ez = fexp2(cn * (2.f * L2E));          // e^2c
                float hn = (ez - 1.f) * frcp((1.f + ew) * (1.f + ez));
                hn4[j] = hn;
            }
            hd[2 * p + 0] = cvtpk(hn4[0], hn4[1]);
            hd[2 * p + 1] = cvtpk(hn4[2], hn4[3]);
        }
    }

    // ---- head: lane (c,g) holds h[8g..8g+7] of batch c ----
    float hfin[8];
#pragma unroll
    for (int d = 0; d < 4; ++d) {
        hfin[2 * d + 0] = __uint_as_float(hd[d] << 16);
        hfin[2 * d + 1] = __uint_as_float(hd[d] & 0xFFFF0000u);
    }
    float hid[16];
#pragma unroll
    for (int q = 0; q < 16; ++q) {
        const float* wr = w1s + q * 32 + g * 8;   // uniform per g: broadcast
        float s = 0.f;
#pragma unroll
        for (int k = 0; k < 8; ++k) s = fmaf(wr[k], hfin[k], s);
        s += __shfl_xor(s, 16);
        s += __shfl_xor(s, 32);
        hid[q] = s;
    }
    float po = b2s;
#pragma unroll
    for (int q = 0; q < 16; ++q)
        po = fmaf(fmaxf(hid[q] + b1s[q], 0.f), w2s[q], po);
    if (g == 0) out[blockBase + xidx] = po;
}

extern "C" void kernel_launch(void* const* d_in, const int* in_sizes, int n_in,
                              void* d_out, int out_size, void* d_ws, size_t ws_size,
                              hipStream_t stream) {
    (void)in_sizes; (void)n_in; (void)d_ws; (void)ws_size; (void)out_size;
    const float* x    = (const float*)d_in[0];
    const float* w_ih = (const float*)d_in[1];
    const float* w_hh = (const float*)d_in[2];
    const float* b_ih = (const float*)d_in[3];
    const float* b_hh = (const float*)d_in[4];
    const float* w1   = (const float*)d_in[5];
    const float* b1   = (const float*)d_in[6];
    const float* w2   = (const float*)d_in[7];
    const float* b2   = (const float*)d_in[8];
    float* outp = (float*)d_out;

    dim3 grid(131072 / 64);   // 64 batch rows per block (4 waves x 16)
    dim3 block(256);
    hipLaunchKernelGGL(lstm_fused, grid, block, 0, stream,
                       x, w_ih, w_hh, b_ih, b_hh, w1, b1, w2, b2, outp);
}

// Round 3
// 107.088 us; speedup vs baseline: 1.2988x; 1.0125x over previous
//
#include <hip/hip_runtime.h>

// LSTM (B=131072, T=24, input=3, H=32) + Linear(32,16)+ReLU+Linear(16,1)
//
// gates^T = Whh * h^T (mfma 16x16x32 bf16) + Wib * [x;1]^T (mfma 16x16x16 bf16).
// Weight A-frags resident in VGPRs. Unit->row permutation makes each lane's
// MFMA outputs exactly the h units it feeds back as B-frag k-slots next step:
// zero cross-lane h traffic, no per-step barrier. Weights prescaled by log2e
// (2*log2e for g gate); c-state kept in 2*log2e-scaled domain so ez=exp2(cs).

typedef short bf16x8 __attribute__((ext_vector_type(8)));
typedef short bf16x4 __attribute__((ext_vector_type(4)));
typedef float f32x4 __attribute__((ext_vector_type(4)));

#define L2E 1.4426950408889634f

#if __has_builtin(__builtin_amdgcn_mfma_f32_16x16x16bf16_1k)
#define HAVE_MFMA16 1
#else
#define HAVE_MFMA16 0
#endif

__device__ __forceinline__ unsigned f2bf(float f) {
    unsigned u = __float_as_uint(f);
    return (u + 0x7FFFu + ((u >> 16) & 1u)) >> 16;   // RNE to bf16
}
__device__ __forceinline__ float fexp2(float v) { return __builtin_amdgcn_exp2f(v); }
__device__ __forceinline__ float frcp(float v)  { return __builtin_amdgcn_rcpf(v); }
__device__ __forceinline__ unsigned cvtpk(float lo, float hi) {
    unsigned r;
    asm("v_cvt_pk_bf16_f32 %0, %1, %2" : "=v"(r) : "v"(lo), "v"(hi));
    return r;
}

__global__ __launch_bounds__(256, 4)
void lstm_fused(const float* __restrict__ x,
                const float* __restrict__ w_ih,
                const float* __restrict__ w_hh,
                const float* __restrict__ b_ih,
                const float* __restrict__ b_hh,
                const float* __restrict__ w1,
                const float* __restrict__ b1,
                const float* __restrict__ w2,
                const float* __restrict__ b2,
                float* __restrict__ out)
{
    __shared__ int2  xq[24 * 64];   // [t][n] packed bf16 {x0,x1 | x2,1.0} (12 KB)
    __shared__ float w1s[512];
    __shared__ float b1s[16];
    __shared__ float w2s[16];
    __shared__ float b2s;

    const int tid  = threadIdx.x;
    const int lane = tid & 63;
    const int wv   = tid >> 6;      // wave id 0..3
    const int c    = lane & 15;     // batch column within wave tile
    const int g    = lane >> 4;     // k-group 0..3
    const int blockBase = blockIdx.x * 64;

    for (int i = tid; i < 512; i += 256) w1s[i] = w1[i];
    if (tid < 16) { b1s[tid] = b1[tid]; w2s[tid] = w2[tid]; }
    if (tid == 16) b2s = b2[0];

    // ---- stage x: pack (x0,x1,x2,1.0) as bf16 per (row, t) ----
    for (int it = 0; it < 6; ++it) {
        int p = tid + it * 256;          // 0..1535 = 64 rows * 24 steps
        int n = p / 24;
        int t = p - n * 24;
        const float* xp = x + ((blockBase + n) * 24 + t) * 3;
        unsigned lo = f2bf(xp[0]) | (f2bf(xp[1]) << 16);
        unsigned hi = f2bf(xp[2]) | (0x3F80u << 16);   // 1.0bf16 hits bias col
        xq[t * 64 + n] = make_int2((int)lo, (int)hi);
    }

    // ---- preload weight A-frags (wave-uniform, permuted rows, prescaled) ----
    // MFMA (G,p) row r computes unit(r,p) = 8*(r>>2) + 4p + (r&3).
    // whh element e = W[row=c][k = 8g+e]; wib element e = k = 4g+e (K=16 frag).
    bf16x8 whh[8];
#if HAVE_MFMA16
    bf16x4 wib[8];
#else
    bf16x8 wib[8];
#endif
    const int ubase = 8 * (c >> 2) + (c & 3);
#pragma unroll
    for (int G = 0; G < 4; ++G) {
        const float scale = (G == 2) ? (2.f * L2E) : L2E;
#pragma unroll
        for (int p = 0; p < 2; ++p) {
            const int row = G * 32 + ubase + 4 * p;
            const float* wr = w_hh + row * 32 + g * 8;
            bf16x8 a;
#pragma unroll
            for (int e = 0; e < 8; ++e) a[e] = (short)f2bf(wr[e] * scale);
            whh[G * 2 + p] = a;
            short c0 = 0, c1 = 0, c2 = 0, c3 = 0;
            if (g == 0) {
                c0 = (short)f2bf(w_ih[row * 3 + 0] * scale);
                c1 = (short)f2bf(w_ih[row * 3 + 1] * scale);
                c2 = (short)f2bf(w_ih[row * 3 + 2] * scale);
                c3 = (short)f2bf((b_ih[row] + b_hh[row]) * scale);
            }
#if HAVE_MFMA16
            bf16x4 bb = {c0, c1, c2, c3};
#else
            bf16x8 bb = {c0, c1, c2, c3, 0, 0, 0, 0};
#endif
            wib[G * 2 + p] = bb;
        }
    }

    __syncthreads();   // xq/w1s staged (only barrier in the kernel)

    float cst[8];                        // 2*L2E-scaled c-state, units 8g+(4p+j)
#pragma unroll
    for (int i = 0; i < 8; ++i) cst[i] = 0.f;

    unsigned hd[4] = {0u, 0u, 0u, 0u};   // packed bf16 h[8g..8g+7] (B-frag)
    const int xidx = wv * 16 + c;

#pragma unroll 1
    for (int t = 0; t < 24; ++t) {
        int2 xv = xq[t * 64 + xidx];     // broadcast across g: conflict-free
        union { int4 i4; bf16x8 v; } hu;
        hu.i4 = make_int4((int)hd[0], (int)hd[1], (int)hd[2], (int)hd[3]);
        bf16x8 hf = hu.v;
        int xlo = (g == 0) ? xv.x : 0;
        int xhi = (g == 0) ? xv.y : 0;
#if HAVE_MFMA16
        union { int2 i2; bf16x4 v; } xu;
        xu.i2 = make_int2(xlo, xhi);
        bf16x4 xf = xu.v;
#else
        union { int4 i4; bf16x8 v; } xu;
        xu.i4 = make_int4(xlo, xhi, 0, 0);
        bf16x8 xf = xu.v;
#endif

#pragma unroll
        for (int p = 0; p < 2; ++p) {
            f32x4 z = {0.f, 0.f, 0.f, 0.f};
            f32x4 ai = z, af = z, ag = z, ao = z;
            ai = __builtin_amdgcn_mfma_f32_16x16x32_bf16(whh[0 + p], hf, ai, 0, 0, 0);
            af = __builtin_amdgcn_mfma_f32_16x16x32_bf16(whh[2 + p], hf, af, 0, 0, 0);
            ag = __builtin_amdgcn_mfma_f32_16x16x32_bf16(whh[4 + p], hf, ag, 0, 0, 0);
            ao = __builtin_amdgcn_mfma_f32_16x16x32_bf16(whh[6 + p], hf, ao, 0, 0, 0);
#if HAVE_MFMA16
            ai = __builtin_amdgcn_mfma_f32_16x16x16bf16_1k(wib[0 + p], xf, ai, 0, 0, 0);
            af = __builtin_amdgcn_mfma_f32_16x16x16bf16_1k(wib[2 + p], xf, af, 0, 0, 0);
            ag = __builtin_amdgcn_mfma_f32_16x16x16bf16_1k(wib[4 + p], xf, ag, 0, 0, 0);
            ao = __builtin_amdgcn_mfma_f32_16x16x16bf16_1k(wib[6 + p], xf, ao, 0, 0, 0);
#else
            ai = __builtin_amdgcn_mfma_f32_16x16x32_bf16(wib[0 + p], xf, ai, 0, 0, 0);
            af = __builtin_amdgcn_mfma_f32_16x16x32_bf16(wib[2 + p], xf, af, 0, 0, 0);
            ag = __builtin_amdgcn_mfma_f32_16x16x32_bf16(wib[4 + p], xf, ag, 0, 0, 0);
            ao = __builtin_amdgcn_mfma_f32_16x16x32_bf16(wib[6 + p], xf, ao, 0, 0, 0);
#endif

            float hn4[4];
#pragma unroll
            for (int j = 0; j < 4; ++j) {
                // lane's value j of half p = preact of unit 8g+4p+j, batch c
                float vi = ai[j], vf = af[j], vg = ag[j], vo = ao[j];
                float ex = fexp2(-vi);            // e^-i   (prescaled L2E)
                float ey = fexp2(vg);             // e^2g   (prescaled 2L2E)
                float ef = fexp2(-vf);            // e^-f
                float axy = (1.f + ex) * (1.f + ey);
                float efp = 1.f + ef;
                float r1  = frcp(axy * efp);
                float igs = fmaf(ey, 2.f * L2E, -2.f * L2E) * efp * r1; // 2L2E*sig(i)tanh(g)
                float fs  = axy * r1;                                   // sig(f)
                float cs  = fmaf(fs, cst[4 * p + j], igs);              // scaled c
                cst[4 * p + j] = cs;
                float ew = fexp2(-vo);            // e^-o
                float ez = fexp2(cs);             // e^2c  (state pre-scaled)
                float hn = (ez - 1.f) * frcp((1.f + ew) * (1.f + ez));
                hn4[j] = hn;
            }
            hd[2 * p + 0] = cvtpk(hn4[0], hn4[1]);
            hd[2 * p + 1] = cvtpk(hn4[2], hn4[3]);
        }
    }

    // ---- head: lane (c,g) holds h[8g..8g+7] of batch c ----
    float hfin[8];
#pragma unroll
    for (int d = 0; d < 4; ++d) {
        hfin[2 * d + 0] = __uint_as_float(hd[d] << 16);
        hfin[2 * d + 1] = __uint_as_float(hd[d] & 0xFFFF0000u);
    }
    float hid[16];
#pragma unroll
    for (int q = 0; q < 16; ++q) {
        const float4* wrow = (const float4*)(w1s + q * 32 + g * 8);
        float4 wa = wrow[0], wb = wrow[1];
        float s = wa.x * hfin[0] + wa.y * hfin[1] + wa.z * hfin[2] + wa.w * hfin[3]
                + wb.x * hfin[4] + wb.y * hfin[5] + wb.z * hfin[6] + wb.w * hfin[7];
        s += __shfl_xor(s, 16);
        s += __shfl_xor(s, 32);
        hid[q] = s;
    }
    float po = b2s;
#pragma unroll
    for (int q = 0; q < 16; ++q)
        po = fmaf(fmaxf(hid[q] + b1s[q], 0.f), w2s[q], po);
    if (g == 0) out[blockBase + xidx] = po;
}

extern "C" void kernel_launch(void* const* d_in, const int* in_sizes, int n_in,
                              void* d_out, int out_size, void* d_ws, size_t ws_size,
                              hipStream_t stream) {
    (void)in_sizes; (void)n_in; (void)d_ws; (void)ws_size; (void)out_size;
    const float* x    = (const float*)d_in[0];
    const float* w_ih = (const float*)d_in[1];
    const float* w_hh = (const float*)d_in[2];
    const float* b_ih = (const float*)d_in[3];
    const float* b_hh = (const float*)d_in[4];
    const float* w1   = (const float*)d_in[5];
    const float* b1   = (const float*)d_in[6];
    const float* w2   = (const float*)d_in[7];
    const float* b2   = (const float*)d_in[8];
    float* outp = (float*)d_out;

    dim3 grid(131072 / 64);   // 64 batch rows per block (4 waves x 16)
    dim3 block(256);
    hipLaunchKernelGGL(lstm_fused, grid, block, 0, stream,
                       x, w_ih, w_hh, b_ih, b_hh, w1, b1, w2, b2, outp);
}

// Round 4
// 105.818 us; speedup vs baseline: 1.3144x; 1.0120x over previous
//
#include <hip/hip_runtime.h>

// LSTM (B=131072, T=24, input=3, H=32) + Linear(32,16)+ReLU+Linear(16,1)
//
// gates^T = Whh * h^T (mfma 16x16x32 bf16) + Wib * [x;1]^T (mfma 16x16x16 bf16).
// Weight A-frags resident in VGPRs. Unit->row permutation makes each lane's
// MFMA outputs exactly the h units it feeds back as B-frag k-slots next step:
// zero cross-lane h traffic, no per-step barrier. Weights prescaled by log2e
// (2*log2e for g gate); c-state kept in 2*log2e-scaled domain so ez=exp2(cs).
// Activation math on f32x2 pairs -> v_pk_{fma,add,mul}_f32. x prefetched 1 step.

typedef short bf16x8 __attribute__((ext_vector_type(8)));
typedef short bf16x4 __attribute__((ext_vector_type(4)));
typedef float f32x4 __attribute__((ext_vector_type(4)));
typedef float f32x2 __attribute__((ext_vector_type(2)));

#define L2E 1.4426950408889634f

#if __has_builtin(__builtin_amdgcn_mfma_f32_16x16x16bf16_1k)
#define HAVE_MFMA16 1
#else
#define HAVE_MFMA16 0
#endif

__device__ __forceinline__ unsigned f2bf(float f) {
    unsigned u = __float_as_uint(f);
    return (u + 0x7FFFu + ((u >> 16) & 1u)) >> 16;   // RNE to bf16
}
__device__ __forceinline__ float fexp2(float v) { return __builtin_amdgcn_exp2f(v); }
__device__ __forceinline__ float frcp(float v)  { return __builtin_amdgcn_rcpf(v); }
__device__ __forceinline__ unsigned cvtpk(float lo, float hi) {
    unsigned r;
    asm("v_cvt_pk_bf16_f32 %0, %1, %2" : "=v"(r) : "v"(lo), "v"(hi));
    return r;
}

// Fused LSTM cell activation for a PAIR of units (packed-f32 friendly).
// Inputs are prescaled: vi,vf,vo by L2E; vg by 2*L2E. cc is 2*L2E-scaled c.
// Returns packed bf16 {h0, h1}.
__device__ __forceinline__ unsigned act2(f32x2 vi, f32x2 vf, f32x2 vg, f32x2 vo,
                                         f32x2& cc)
{
    f32x2 ex, ey, ef, ew, ez, r1, r2;
    ex[0] = fexp2(-vi[0]); ex[1] = fexp2(-vi[1]);   // e^-i
    ey[0] = fexp2(vg[0]);  ey[1] = fexp2(vg[1]);    // e^2g
    ef[0] = fexp2(-vf[0]); ef[1] = fexp2(-vf[1]);   // e^-f
    const f32x2 one = {1.f, 1.f};
    f32x2 axy = (one + ex) * (one + ey);
    f32x2 efp = one + ef;
    f32x2 dd  = axy * efp;
    r1[0] = frcp(dd[0]); r1[1] = frcp(dd[1]);
    const f32x2 K2 = {2.f * L2E, 2.f * L2E};
    f32x2 igs = (ey * K2 - K2) * efp * r1;          // 2L2E*sig(i)*tanh(g)
    f32x2 fs  = axy * r1;                           // sig(f)
    cc = fs * cc + igs;                             // scaled c update (pk_fma)
    ew[0] = fexp2(-vo[0]); ew[1] = fexp2(-vo[1]);   // e^-o
    ez[0] = fexp2(cc[0]);  ez[1] = fexp2(cc[1]);    // e^2c
    f32x2 d2 = (one + ew) * (one + ez);
    r2[0] = frcp(d2[0]); r2[1] = frcp(d2[1]);
    f32x2 hn = (ez - one) * r2;                     // sig(o)*tanh(c)
    return cvtpk(hn[0], hn[1]);
}

__global__ __launch_bounds__(256, 4)
void lstm_fused(const float* __restrict__ x,
                const float* __restrict__ w_ih,
                const float* __restrict__ w_hh,
                const float* __restrict__ b_ih,
                const float* __restrict__ b_hh,
                const float* __restrict__ w1,
                const float* __restrict__ b1,
                const float* __restrict__ w2,
                const float* __restrict__ b2,
                float* __restrict__ out)
{
    __shared__ int2  xq[24 * 64];   // [t][n] packed bf16 {x0,x1 | x2,1.0} (12 KB)
    __shared__ float w1s[512];
    __shared__ float b1s[16];
    __shared__ float w2s[16];
    __shared__ float b2s;

    const int tid  = threadIdx.x;
    const int lane = tid & 63;
    const int wv   = tid >> 6;      // wave id 0..3
    const int c    = lane & 15;     // batch column within wave tile
    const int g    = lane >> 4;     // k-group 0..3
    const int blockBase = blockIdx.x * 64;

    for (int i = tid; i < 512; i += 256) w1s[i] = w1[i];
    if (tid < 16) { b1s[tid] = b1[tid]; w2s[tid] = w2[tid]; }
    if (tid == 16) b2s = b2[0];

    // ---- stage x: pack (x0,x1,x2,1.0) as bf16 per (row, t) ----
    for (int it = 0; it < 6; ++it) {
        int p = tid + it * 256;          // 0..1535 = 64 rows * 24 steps
        int n = p / 24;
        int t = p - n * 24;
        const float* xp = x + ((blockBase + n) * 24 + t) * 3;
        unsigned lo = f2bf(xp[0]) | (f2bf(xp[1]) << 16);
        unsigned hi = f2bf(xp[2]) | (0x3F80u << 16);   // 1.0bf16 hits bias col
        xq[t * 64 + n] = make_int2((int)lo, (int)hi);
    }

    // ---- preload weight A-frags (wave-uniform, permuted rows, prescaled) ----
    // MFMA (G,p) row r computes unit(r,p) = 8*(r>>2) + 4p + (r&3).
    // whh element e = W[row=c][k = 8g+e]; wib element e = k = 4g+e (K=16 frag).
    bf16x8 whh[8];
#if HAVE_MFMA16
    bf16x4 wib[8];
#else
    bf16x8 wib[8];
#endif
    const int ubase = 8 * (c >> 2) + (c & 3);
#pragma unroll
    for (int G = 0; G < 4; ++G) {
        const float scale = (G == 2) ? (2.f * L2E) : L2E;
#pragma unroll
        for (int p = 0; p < 2; ++p) {
            const int row = G * 32 + ubase + 4 * p;
            const float* wr = w_hh + row * 32 + g * 8;
            bf16x8 a;
#pragma unroll
            for (int e = 0; e < 8; ++e) a[e] = (short)f2bf(wr[e] * scale);
            whh[G * 2 + p] = a;
            short c0 = 0, c1 = 0, c2 = 0, c3 = 0;
            if (g == 0) {
                c0 = (short)f2bf(w_ih[row * 3 + 0] * scale);
                c1 = (short)f2bf(w_ih[row * 3 + 1] * scale);
                c2 = (short)f2bf(w_ih[row * 3 + 2] * scale);
                c3 = (short)f2bf((b_ih[row] + b_hh[row]) * scale);
            }
#if HAVE_MFMA16
            bf16x4 bb = {c0, c1, c2, c3};
#else
            bf16x8 bb = {c0, c1, c2, c3, 0, 0, 0, 0};
#endif
            wib[G * 2 + p] = bb;
        }
    }

    __syncthreads();   // xq/w1s staged (only barrier in the kernel)

    f32x2 cz = {0.f, 0.f};
    f32x2 cst2[4] = {cz, cz, cz, cz};    // scaled c-state pairs

    union { unsigned u[4]; bf16x8 v; } hreg;   // packed bf16 h[8g..8g+7] B-frag
    hreg.u[0] = hreg.u[1] = hreg.u[2] = hreg.u[3] = 0u;

    const int xidx = wv * 16 + c;
    int2 xv = xq[xidx];                  // t = 0

#pragma unroll 1
    for (int t = 0; t < 24; ++t) {
        const int tn = (t < 23) ? t + 1 : 23;
        int2 xnxt = xq[tn * 64 + xidx];  // prefetch next step (broadcast, clean)

        bf16x8 hf = hreg.v;
        int xlo = (g == 0) ? xv.x : 0;
        int xhi = (g == 0) ? xv.y : 0;
#if HAVE_MFMA16
        union { int2 i2; bf16x4 v; } xu;
        xu.i2 = make_int2(xlo, xhi);
        bf16x4 xf = xu.v;
#else
        union { int4 i4; bf16x8 v; } xu;
        xu.i4 = make_int4(xlo, xhi, 0, 0);
        bf16x8 xf = xu.v;
#endif

#pragma unroll
        for (int p = 0; p < 2; ++p) {
            f32x4 z = {0.f, 0.f, 0.f, 0.f};
            f32x4 ai = z, af = z, ag = z, ao = z;
            ai = __builtin_amdgcn_mfma_f32_16x16x32_bf16(whh[0 + p], hf, ai, 0, 0, 0);
            af = __builtin_amdgcn_mfma_f32_16x16x32_bf16(whh[2 + p], hf, af, 0, 0, 0);
            ag = __builtin_amdgcn_mfma_f32_16x16x32_bf16(whh[4 + p], hf, ag, 0, 0, 0);
            ao = __builtin_amdgcn_mfma_f32_16x16x32_bf16(whh[6 + p], hf, ao, 0, 0, 0);
#if HAVE_MFMA16
            ai = __builtin_amdgcn_mfma_f32_16x16x16bf16_1k(wib[0 + p], xf, ai, 0, 0, 0);
            af = __builtin_amdgcn_mfma_f32_16x16x16bf16_1k(wib[2 + p], xf, af, 0, 0, 0);
            ag = __builtin_amdgcn_mfma_f32_16x16x16bf16_1k(wib[4 + p], xf, ag, 0, 0, 0);
            ao = __builtin_amdgcn_mfma_f32_16x16x16bf16_1k(wib[6 + p], xf, ao, 0, 0, 0);
#else
            ai = __builtin_amdgcn_mfma_f32_16x16x32_bf16(wib[0 + p], xf, ai, 0, 0, 0);
            af = __builtin_amdgcn_mfma_f32_16x16x32_bf16(wib[2 + p], xf, af, 0, 0, 0);
            ag = __builtin_amdgcn_mfma_f32_16x16x32_bf16(wib[4 + p], xf, ag, 0, 0, 0);
            ao = __builtin_amdgcn_mfma_f32_16x16x32_bf16(wib[6 + p], xf, ao, 0, 0, 0);
#endif
            // units 8g+4p+{0,1} and 8g+4p+{2,3} as packed pairs
            f32x2 vi0 = {ai[0], ai[1]}, vi1 = {ai[2], ai[3]};
            f32x2 vf0 = {af[0], af[1]}, vf1 = {af[2], af[3]};
            f32x2 vg0 = {ag[0], ag[1]}, vg1 = {ag[2], ag[3]};
            f32x2 vo0 = {ao[0], ao[1]}, vo1 = {ao[2], ao[3]};
            hreg.u[2 * p + 0] = act2(vi0, vf0, vg0, vo0, cst2[2 * p + 0]);
            hreg.u[2 * p + 1] = act2(vi1, vf1, vg1, vo1, cst2[2 * p + 1]);
        }
        xv = xnxt;
    }

    // ---- head: lane (c,g) holds h[8g..8g+7] of batch c ----
    float hfin[8];
#pragma unroll
    for (int d = 0; d < 4; ++d) {
        hfin[2 * d + 0] = __uint_as_float(hreg.u[d] << 16);
        hfin[2 * d + 1] = __uint_as_float(hreg.u[d] & 0xFFFF0000u);
    }
    float hid[16];
#pragma unroll
    for (int q = 0; q < 16; ++q) {
        const float4* wrow = (const float4*)(w1s + q * 32 + g * 8);
        float4 wa = wrow[0], wb = wrow[1];
        float s = wa.x * hfin[0] + wa.y * hfin[1] + wa.z * hfin[2] + wa.w * hfin[3]
                + wb.x * hfin[4] + wb.y * hfin[5] + wb.z * hfin[6] + wb.w * hfin[7];
        s += __shfl_xor(s, 16);
        s += __shfl_xor(s, 32);
        hid[q] = s;
    }
    float po = b2s;
#pragma unroll
    for (int q = 0; q < 16; ++q)
        po = fmaf(fmaxf(hid[q] + b1s[q], 0.f), w2s[q], po);
    if (g == 0) out[blockBase + xidx] = po;
}

extern "C" void kernel_launch(void* const* d_in, const int* in_sizes, int n_in,
                              void* d_out, int out_size, void* d_ws, size_t ws_size,
                              hipStream_t stream) {
    (void)in_sizes; (void)n_in; (void)d_ws; (void)ws_size; (void)out_size;
    const float* x    = (const float*)d_in[0];
    const float* w_ih = (const float*)d_in[1];
    const float* w_hh = (const float*)d_in[2];
    const float* b_ih = (const float*)d_in[3];
    const float* b_hh = (const float*)d_in[4];
    const float* w1   = (const float*)d_in[5];
    const float* b1   = (const float*)d_in[6];
    const float* w2   = (const float*)d_in[7];
    const float* b2   = (const float*)d_in[8];
    float* outp = (float*)d_out;

    dim3 grid(131072 / 64);   // 64 batch rows per block (4 waves x 16)
    dim3 block(256);
    hipLaunchKernelGGL(lstm_fused, grid, block, 0, stream,
                       x, w_ih, w_hh, b_ih, b_hh, w1, b1, w2, b2, outp);
}

// Round 6
// 102.660 us; speedup vs baseline: 1.3548x; 1.0308x over previous
//
#include <hip/hip_runtime.h>

// LSTM (B=131072, T=24, input=3, H=32) + Linear(32,16)+ReLU+Linear(16,1)
//
// gates^T = Whh * h^T (mfma 16x16x32 f16) + Wib * [x;1]^T (mfma 16x16x16 f16).
// FP16 (not bf16): 10 mantissa bits -> 8x smaller h/w/x quantization error,
// robust to scheduling-dependent rounding in the recurrence (R5 lesson).
// Weight A-frags resident in VGPRs, SHARED by two independent batch streams
// per wave (2x ILP to cover the per-step dependency chain: MFMA->exp2->rcp->
// fma->exp2->rcp->next MFMA). Unit->row permutation makes each lane's MFMA
// outputs exactly the h units it feeds back as B-frag k-slots next step:
// zero cross-lane h traffic, no per-step barrier. Weights prescaled by log2e
// (2*log2e for g gate); c-state kept in 2*log2e domain so ez=exp2(cs).

typedef _Float16 f16x8 __attribute__((ext_vector_type(8)));
typedef _Float16 f16x4 __attribute__((ext_vector_type(4)));
typedef _Float16 f16x2 __attribute__((ext_vector_type(2)));
typedef float f32x4 __attribute__((ext_vector_type(4)));
typedef float f32x2 __attribute__((ext_vector_type(2)));

#define L2E 1.4426950408889634f

#if __has_builtin(__builtin_amdgcn_mfma_f32_16x16x16f16)
#define HAVE_MFMA16 1
#else
#define HAVE_MFMA16 0
#endif

__device__ __forceinline__ float fexp2(float v) { return __builtin_amdgcn_exp2f(v); }
__device__ __forceinline__ float frcp(float v)  { return __builtin_amdgcn_rcpf(v); }

// LSTM cell activation for a PAIR of units. Inputs prescaled: vi,vf,vo by L2E;
// vg by 2*L2E. cc is the 2*L2E-scaled c-state. Returns f16 pair {h0,h1}.
__device__ __forceinline__ f16x2 act2(f32x2 vi, f32x2 vf, f32x2 vg, f32x2 vo,
                                      f32x2& cc)
{
    f32x2 ex, ey, ef, ew, ez, r1, r2;
    ex[0] = fexp2(-vi[0]); ex[1] = fexp2(-vi[1]);   // e^-i
    ey[0] = fexp2(vg[0]);  ey[1] = fexp2(vg[1]);    // e^2g
    ef[0] = fexp2(-vf[0]); ef[1] = fexp2(-vf[1]);   // e^-f
    const f32x2 one = {1.f, 1.f};
    f32x2 axy = (one + ex) * (one + ey);
    f32x2 efp = one + ef;
    f32x2 dd  = axy * efp;
    r1[0] = frcp(dd[0]); r1[1] = frcp(dd[1]);
    const f32x2 K2 = {2.f * L2E, 2.f * L2E};
    f32x2 igs = (ey * K2 - K2) * efp * r1;          // 2L2E*sig(i)*tanh(g)
    f32x2 fs  = axy * r1;                           // sig(f)
    cc = fs * cc + igs;                             // scaled c update (pk_fma)
    ew[0] = fexp2(-vo[0]); ew[1] = fexp2(-vo[1]);   // e^-o
    ez[0] = fexp2(cc[0]);  ez[1] = fexp2(cc[1]);    // e^2c
    f32x2 d2 = (one + ew) * (one + ez);
    r2[0] = frcp(d2[0]); r2[1] = frcp(d2[1]);
    f32x2 hn = (ez - one) * r2;                     // sig(o)*tanh(c)
    f16x2 r; r[0] = (_Float16)hn[0]; r[1] = (_Float16)hn[1];
    return r;
}

__global__ __launch_bounds__(256, 3)
void lstm_fused(const float* __restrict__ x,
                const float* __restrict__ w_ih,
                const float* __restrict__ w_hh,
                const float* __restrict__ b_ih,
                const float* __restrict__ b_hh,
                const float* __restrict__ w1,
                const float* __restrict__ b1,
                const float* __restrict__ w2,
                const float* __restrict__ b2,
                float* __restrict__ out)
{
    __shared__ int2  xq[24 * 128];  // [t][n] packed f16 {x0,x1 | x2,1.0} (24 KB)
    __shared__ float w1s[512];
    __shared__ float b1s[16];
    __shared__ float w2s[16];
    __shared__ float b2s;

    const int tid  = threadIdx.x;
    const int lane = tid & 63;
    const int wv   = tid >> 6;      // wave id 0..3
    const int c    = lane & 15;     // batch column within wave tile
    const int g    = lane >> 4;     // k-group 0..3
    const int blockBase = blockIdx.x * 128;

    for (int i = tid; i < 512; i += 256) w1s[i] = w1[i];
    if (tid < 16) { b1s[tid] = b1[tid]; w2s[tid] = w2[tid]; }
    if (tid == 16) b2s = b2[0];

    // ---- stage x: pack (x0,x1,x2,1.0) as f16 per (row, t) ----
    for (int it = 0; it < 12; ++it) {
        int p = tid + it * 256;          // 0..3071 = 128 rows * 24 steps
        int n = p / 24;
        int t = p - n * 24;
        const float* xp = x + ((blockBase + n) * 24 + t) * 3;
        union { f16x4 h; int2 i2; } tq;
        tq.h[0] = (_Float16)xp[0];
        tq.h[1] = (_Float16)xp[1];
        tq.h[2] = (_Float16)xp[2];
        tq.h[3] = (_Float16)1.0f;        // hits fused-bias column
        xq[t * 128 + n] = tq.i2;
    }

    // ---- preload weight A-frags (wave-uniform, permuted rows, prescaled) ----
    // MFMA (G,p) row r computes unit(r,p) = 8*(r>>2) + 4p + (r&3).
    // whh element e = W[row=c][k = 8g+e]; wib element e = k = 4g+e (K=16 frag).
    f16x8 whh[8];
#if HAVE_MFMA16
    f16x4 wib[8];
#else
    f16x8 wib[8];
#endif
    const int ubase = 8 * (c >> 2) + (c & 3);
#pragma unroll
    for (int G = 0; G < 4; ++G) {
        const float scale = (G == 2) ? (2.f * L2E) : L2E;
#pragma unroll
        for (int p = 0; p < 2; ++p) {
            const int row = G * 32 + ubase + 4 * p;
            const float* wr = w_hh + row * 32 + g * 8;
            f16x8 a;
#pragma unroll
            for (int e = 0; e < 8; ++e) a[e] = (_Float16)(wr[e] * scale);
            whh[G * 2 + p] = a;
            _Float16 c0 = 0, c1 = 0, c2 = 0, c3 = 0;
            if (g == 0) {
                c0 = (_Float16)(w_ih[row * 3 + 0] * scale);
                c1 = (_Float16)(w_ih[row * 3 + 1] * scale);
                c2 = (_Float16)(w_ih[row * 3 + 2] * scale);
                c3 = (_Float16)((b_ih[row] + b_hh[row]) * scale);
            }
#if HAVE_MFMA16
            f16x4 bb = {c0, c1, c2, c3};
#else
            f16x8 bb = {c0, c1, c2, c3, 0, 0, 0, 0};
#endif
            wib[G * 2 + p] = bb;
        }
    }

    __syncthreads();   // xq/w1s staged (only barrier in the kernel)

    // ---- two independent batch streams per wave ----
    f32x2 cz = {0.f, 0.f};
    f32x2 cst2[2][4] = {{cz, cz, cz, cz}, {cz, cz, cz, cz}};
    union hu_t { f16x2 p2[4]; f16x8 v; int4 i4; } hreg[2];
#pragma unroll
    for (int s = 0; s < 2; ++s) hreg[s].i4 = make_int4(0, 0, 0, 0);

    const int n0 = wv * 16 + c;          // stream 0 column
    int2 xv[2];
    xv[0] = xq[n0];
    xv[1] = xq[n0 + 64];

#pragma unroll 1
    for (int t = 0; t < 24; ++t) {
        const int tn = (t < 23) ? t + 1 : 23;
        int2 xn0 = xq[tn * 128 + n0];        // prefetch next step
        int2 xn1 = xq[tn * 128 + n0 + 64];

#pragma unroll
        for (int s = 0; s < 2; ++s) {
            f16x8 hf = hreg[s].v;
            int xlo = (g == 0) ? xv[s].x : 0;
            int xhi = (g == 0) ? xv[s].y : 0;
#if HAVE_MFMA16
            union { int2 i2; f16x4 v; } xu;
            xu.i2 = make_int2(xlo, xhi);
            f16x4 xf = xu.v;
#else
            union { int4 i4; f16x8 v; } xu;
            xu.i4 = make_int4(xlo, xhi, 0, 0);
            f16x8 xf = xu.v;
#endif

#pragma unroll
            for (int p = 0; p < 2; ++p) {
                f32x4 z = {0.f, 0.f, 0.f, 0.f};
                f32x4 ai = z, af = z, ag = z, ao = z;
                ai = __builtin_amdgcn_mfma_f32_16x16x32_f16(whh[0 + p], hf, ai, 0, 0, 0);
                af = __builtin_amdgcn_mfma_f32_16x16x32_f16(whh[2 + p], hf, af, 0, 0, 0);
                ag = __builtin_amdgcn_mfma_f32_16x16x32_f16(whh[4 + p], hf, ag, 0, 0, 0);
                ao = __builtin_amdgcn_mfma_f32_16x16x32_f16(whh[6 + p], hf, ao, 0, 0, 0);
#if HAVE_MFMA16
                ai = __builtin_amdgcn_mfma_f32_16x16x16f16(wib[0 + p], xf, ai, 0, 0, 0);
                af = __builtin_amdgcn_mfma_f32_16x16x16f16(wib[2 + p], xf, af, 0, 0, 0);
                ag = __builtin_amdgcn_mfma_f32_16x16x16f16(wib[4 + p], xf, ag, 0, 0, 0);
                ao = __builtin_amdgcn_mfma_f32_16x16x16f16(wib[6 + p], xf, ao, 0, 0, 0);
#else
                ai = __builtin_amdgcn_mfma_f32_16x16x32_f16(wib[0 + p], xf, ai, 0, 0, 0);
                af = __builtin_amdgcn_mfma_f32_16x16x32_f16(wib[2 + p], xf, af, 0, 0, 0);
                ag = __builtin_amdgcn_mfma_f32_16x16x32_f16(wib[4 + p], xf, ag, 0, 0, 0);
                ao = __builtin_amdgcn_mfma_f32_16x16x32_f16(wib[6 + p], xf, ao, 0, 0, 0);
#endif
                f32x2 vi0 = {ai[0], ai[1]}, vi1 = {ai[2], ai[3]};
                f32x2 vf0 = {af[0], af[1]}, vf1 = {af[2], af[3]};
                f32x2 vg0 = {ag[0], ag[1]}, vg1 = {ag[2], ag[3]};
                f32x2 vo0 = {ao[0], ao[1]}, vo1 = {ao[2], ao[3]};
                hreg[s].p2[2 * p + 0] = act2(vi0, vf0, vg0, vo0, cst2[s][2 * p + 0]);
                hreg[s].p2[2 * p + 1] = act2(vi1, vf1, vg1, vo1, cst2[s][2 * p + 1]);
            }
        }
        xv[0] = xn0;
        xv[1] = xn1;
    }

    // ---- head: lane (c,g) holds h[8g..8g+7] of batch columns n0, n0+64 ----
#pragma unroll
    for (int s = 0; s < 2; ++s) {
        float hfin[8];
#pragma unroll
        for (int d = 0; d < 8; ++d) hfin[d] = (float)hreg[s].v[d];
        float hid[16];
#pragma unroll
        for (int q = 0; q < 16; ++q) {
            const float4* wrow = (const float4*)(w1s + q * 32 + g * 8);
            float4 wa = wrow[0], wb = wrow[1];
            float sm = wa.x * hfin[0] + wa.y * hfin[1] + wa.z * hfin[2] + wa.w * hfin[3]
                     + wb.x * hfin[4] + wb.y * hfin[5] + wb.z * hfin[6] + wb.w * hfin[7];
            sm += __shfl_xor(sm, 16);
            sm += __shfl_xor(sm, 32);
            hid[q] = sm;
        }
        float po = b2s;
#pragma unroll
        for (int q = 0; q < 16; ++q)
            po = fmaf(fmaxf(hid[q] + b1s[q], 0.f), w2s[q], po);
        if (g == 0) out[blockBase + s * 64 + n0] = po;
    }
}

extern "C" void kernel_launch(void* const* d_in, const int* in_sizes, int n_in,
                              void* d_out, int out_size, void* d_ws, size_t ws_size,
                              hipStream_t stream) {
    (void)in_sizes; (void)n_in; (void)d_ws; (void)ws_size; (void)out_size;
    const float* x    = (const float*)d_in[0];
    const float* w_ih = (const float*)d_in[1];
    const float* w_hh = (const float*)d_in[2];
    const float* b_ih = (const float*)d_in[3];
    const float* b_hh = (const float*)d_in[4];
    const float* w1   = (const float*)d_in[5];
    const float* b1   = (const float*)d_in[6];
    const float* w2   = (const float*)d_in[7];
    const float* b2   = (const float*)d_in[8];
    float* outp = (float*)d_out;

    dim3 grid(131072 / 128);   // 128 batch rows per block (4 waves x 16 x 2 streams)
    dim3 block(256);
    hipLaunchKernelGGL(lstm_fused, grid, block, 0, stream,
                       x, w_ih, w_hh, b_ih, b_hh, w1, b1, w2, b2, outp);
}

// Round 7
// 100.976 us; speedup vs baseline: 1.3774x; 1.0167x over previous
//
#include <hip/hip_runtime.h>

// LSTM (B=131072, T=24, input=3, H=32) + Linear(32,16)+ReLU+Linear(16,1)
//
// gates^T = Whh * h^T (mfma 16x16x32 f16) + Wib * [x;1]^T (mfma 16x16x16 f16).
// FOUR independent batch streams per wave share one VGPR-resident weight set.
// Total streams/SIMD ~= 8 (2 waves x 4): covers the per-step dependency chain
// MFMA->exp2->rcp->fma->exp2->rcp->next-MFMA that pinned R4-R6 at ~103us.
// Unit->row permutation makes each lane's MFMA outputs exactly the h units it
// feeds back as B-frag k-slots next step: zero cross-lane h traffic, no
// per-step barrier. Weights prescaled by log2e (2*log2e for g gate); c-state
// kept in 2*log2e domain so ez=exp2(cs). FP16 storage for h/w/x (R5 lesson).

typedef _Float16 f16x8 __attribute__((ext_vector_type(8)));
typedef _Float16 f16x4 __attribute__((ext_vector_type(4)));
typedef _Float16 f16x2 __attribute__((ext_vector_type(2)));
typedef float f32x4 __attribute__((ext_vector_type(4)));
typedef float f32x2 __attribute__((ext_vector_type(2)));

#define L2E 1.4426950408889634f

#if __has_builtin(__builtin_amdgcn_mfma_f32_16x16x16f16)
#define HAVE_MFMA16 1
#else
#define HAVE_MFMA16 0
#endif

__device__ __forceinline__ float fexp2(float v) { return __builtin_amdgcn_exp2f(v); }
__device__ __forceinline__ float frcp(float v)  { return __builtin_amdgcn_rcpf(v); }

// LSTM cell activation for a PAIR of units. Inputs prescaled: vi,vf,vo by L2E;
// vg by 2*L2E. cc is the 2*L2E-scaled c-state. Returns f16 pair {h0,h1}.
__device__ __forceinline__ f16x2 act2(f32x2 vi, f32x2 vf, f32x2 vg, f32x2 vo,
                                      f32x2& cc)
{
    f32x2 ex, ey, ef, ew, ez, r1, r2;
    ex[0] = fexp2(-vi[0]); ex[1] = fexp2(-vi[1]);   // e^-i
    ey[0] = fexp2(vg[0]);  ey[1] = fexp2(vg[1]);    // e^2g
    ef[0] = fexp2(-vf[0]); ef[1] = fexp2(-vf[1]);   // e^-f
    const f32x2 one = {1.f, 1.f};
    f32x2 axy = (one + ex) * (one + ey);
    f32x2 efp = one + ef;
    f32x2 dd  = axy * efp;
    r1[0] = frcp(dd[0]); r1[1] = frcp(dd[1]);
    const f32x2 K2 = {2.f * L2E, 2.f * L2E};
    f32x2 igs = (ey * K2 - K2) * efp * r1;          // 2L2E*sig(i)*tanh(g)
    f32x2 fs  = axy * r1;                           // sig(f)
    cc = fs * cc + igs;                             // scaled c update
    ew[0] = fexp2(-vo[0]); ew[1] = fexp2(-vo[1]);   // e^-o
    ez[0] = fexp2(cc[0]);  ez[1] = fexp2(cc[1]);    // e^2c
    f32x2 d2 = (one + ew) * (one + ez);
    r2[0] = frcp(d2[0]); r2[1] = frcp(d2[1]);
    f32x2 hn = (ez - one) * r2;                     // sig(o)*tanh(c)
    f16x2 r; r[0] = (_Float16)hn[0]; r[1] = (_Float16)hn[1];
    return r;
}

__global__ __launch_bounds__(256, 2)
void lstm_fused(const float* __restrict__ x,
                const float* __restrict__ w_ih,
                const float* __restrict__ w_hh,
                const float* __restrict__ b_ih,
                const float* __restrict__ b_hh,
                const float* __restrict__ w1,
                const float* __restrict__ b1,
                const float* __restrict__ w2,
                const float* __restrict__ b2,
                float* __restrict__ out)
{
    __shared__ int2  xq[24 * 256];  // [t][n] packed f16 {x0,x1,x2,1.0} (48 KB)
    __shared__ float w1s[512];
    __shared__ float b1s[16];
    __shared__ float w2s[16];
    __shared__ float b2s;

    const int tid  = threadIdx.x;
    const int lane = tid & 63;
    const int wv   = tid >> 6;      // wave id 0..3
    const int c    = lane & 15;     // batch column within wave tile
    const int g    = lane >> 4;     // k-group 0..3
    const int blockBase = blockIdx.x * 256;

    for (int i = tid; i < 512; i += 256) w1s[i] = w1[i];
    if (tid < 16) { b1s[tid] = b1[tid]; w2s[tid] = w2[tid]; }
    if (tid == 16) b2s = b2[0];

    // ---- stage x: pack (x0,x1,x2,1.0) as f16 per (row, t) ----
    for (int it = 0; it < 24; ++it) {
        int p = tid + it * 256;          // 0..6143 = 256 rows * 24 steps
        int n = p / 24;
        int t = p - n * 24;
        const float* xp = x + ((blockBase + n) * 24 + t) * 3;
        union { f16x4 h; int2 i2; } tq;
        tq.h[0] = (_Float16)xp[0];
        tq.h[1] = (_Float16)xp[1];
        tq.h[2] = (_Float16)xp[2];
        tq.h[3] = (_Float16)1.0f;        // hits fused-bias column
        xq[t * 256 + n] = tq.i2;
    }

    // ---- preload weight A-frags (wave-uniform, permuted rows, prescaled) ----
    // MFMA (G,p) row r computes unit(r,p) = 8*(r>>2) + 4p + (r&3).
    // whh element e = W[row=c][k = 8g+e]; wib element e = k = 4g+e (K=16 frag).
    f16x8 whh[8];
#if HAVE_MFMA16
    f16x4 wib[8];
#else
    f16x8 wib[8];
#endif
    const int ubase = 8 * (c >> 2) + (c & 3);
#pragma unroll
    for (int G = 0; G < 4; ++G) {
        const float scale = (G == 2) ? (2.f * L2E) : L2E;
#pragma unroll
        for (int p = 0; p < 2; ++p) {
            const int row = G * 32 + ubase + 4 * p;
            const float* wr = w_hh + row * 32 + g * 8;
            f16x8 a;
#pragma unroll
            for (int e = 0; e < 8; ++e) a[e] = (_Float16)(wr[e] * scale);
            whh[G * 2 + p] = a;
            _Float16 c0 = 0, c1 = 0, c2 = 0, c3 = 0;
            if (g == 0) {
                c0 = (_Float16)(w_ih[row * 3 + 0] * scale);
                c1 = (_Float16)(w_ih[row * 3 + 1] * scale);
                c2 = (_Float16)(w_ih[row * 3 + 2] * scale);
                c3 = (_Float16)((b_ih[row] + b_hh[row]) * scale);
            }
#if HAVE_MFMA16
            f16x4 bb = {c0, c1, c2, c3};
#else
            f16x8 bb = {c0, c1, c2, c3, 0, 0, 0, 0};
#endif
            wib[G * 2 + p] = bb;
        }
    }

    __syncthreads();   // xq/w1s staged (only barrier in the kernel)

    // ---- four independent batch streams per wave ----
    f32x2 cz = {0.f, 0.f};
    f32x2 cst2[4][4] = {{cz, cz, cz, cz}, {cz, cz, cz, cz},
                        {cz, cz, cz, cz}, {cz, cz, cz, cz}};
    union hu_t { f16x2 p2[4]; f16x8 v; int4 i4; } hreg[4];
#pragma unroll
    for (int s = 0; s < 4; ++s) hreg[s].i4 = make_int4(0, 0, 0, 0);

    const int n0 = wv * 16 + c;          // stream 0 column; stream s: +64*s
    int2 xv[4];
#pragma unroll
    for (int s = 0; s < 4; ++s) xv[s] = xq[n0 + 64 * s];

#pragma unroll 1
    for (int t = 0; t < 24; ++t) {
        const int tn = (t < 23) ? t + 1 : 23;
        int2 xn[4];
#pragma unroll
        for (int s = 0; s < 4; ++s) xn[s] = xq[tn * 256 + n0 + 64 * s];

#pragma unroll
        for (int s = 0; s < 4; ++s) {
            f16x8 hf = hreg[s].v;
            int xlo = (g == 0) ? xv[s].x : 0;
            int xhi = (g == 0) ? xv[s].y : 0;
#if HAVE_MFMA16
            union { int2 i2; f16x4 v; } xu;
            xu.i2 = make_int2(xlo, xhi);
            f16x4 xf = xu.v;
#else
            union { int4 i4; f16x8 v; } xu;
            xu.i4 = make_int4(xlo, xhi, 0, 0);
            f16x8 xf = xu.v;
#endif

#pragma unroll
            for (int p = 0; p < 2; ++p) {
                f32x4 z = {0.f, 0.f, 0.f, 0.f};
                f32x4 ai = z, af = z, ag = z, ao = z;
                ai = __builtin_amdgcn_mfma_f32_16x16x32_f16(whh[0 + p], hf, ai, 0, 0, 0);
                af = __builtin_amdgcn_mfma_f32_16x16x32_f16(whh[2 + p], hf, af, 0, 0, 0);
                ag = __builtin_amdgcn_mfma_f32_16x16x32_f16(whh[4 + p], hf, ag, 0, 0, 0);
                ao = __builtin_amdgcn_mfma_f32_16x16x32_f16(whh[6 + p], hf, ao, 0, 0, 0);
#if HAVE_MFMA16
                ai = __builtin_amdgcn_mfma_f32_16x16x16f16(wib[0 + p], xf, ai, 0, 0, 0);
                af = __builtin_amdgcn_mfma_f32_16x16x16f16(wib[2 + p], xf, af, 0, 0, 0);
                ag = __builtin_amdgcn_mfma_f32_16x16x16f16(wib[4 + p], xf, ag, 0, 0, 0);
                ao = __builtin_amdgcn_mfma_f32_16x16x16f16(wib[6 + p], xf, ao, 0, 0, 0);
#else
                ai = __builtin_amdgcn_mfma_f32_16x16x32_f16(wib[0 + p], xf, ai, 0, 0, 0);
                af = __builtin_amdgcn_mfma_f32_16x16x32_f16(wib[2 + p], xf, af, 0, 0, 0);
                ag = __builtin_amdgcn_mfma_f32_16x16x32_f16(wib[4 + p], xf, ag, 0, 0, 0);
                ao = __builtin_amdgcn_mfma_f32_16x16x32_f16(wib[6 + p], xf, ao, 0, 0, 0);
#endif
                f32x2 vi0 = {ai[0], ai[1]}, vi1 = {ai[2], ai[3]};
                f32x2 vf0 = {af[0], af[1]}, vf1 = {af[2], af[3]};
                f32x2 vg0 = {ag[0], ag[1]}, vg1 = {ag[2], ag[3]};
                f32x2 vo0 = {ao[0], ao[1]}, vo1 = {ao[2], ao[3]};
                hreg[s].p2[2 * p + 0] = act2(vi0, vf0, vg0, vo0, cst2[s][2 * p + 0]);
                hreg[s].p2[2 * p + 1] = act2(vi1, vf1, vg1, vo1, cst2[s][2 * p + 1]);
            }
        }
#pragma unroll
        for (int s = 0; s < 4; ++s) xv[s] = xn[s];
    }

    // ---- head: lane (c,g) holds h[8g..8g+7] of batch cols n0+64s ----
#pragma unroll
    for (int s = 0; s < 4; ++s) {
        float hfin[8];
#pragma unroll
        for (int d = 0; d < 8; ++d) hfin[d] = (float)hreg[s].v[d];
        float hid[16];
#pragma unroll
        for (int q = 0; q < 16; ++q) {
            const float4* wrow = (const float4*)(w1s + q * 32 + g * 8);
            float4 wa = wrow[0], wb = wrow[1];
            float sm = wa.x * hfin[0] + wa.y * hfin[1] + wa.z * hfin[2] + wa.w * hfin[3]
                     + wb.x * hfin[4] + wb.y * hfin[5] + wb.z * hfin[6] + wb.w * hfin[7];
            sm += __shfl_xor(sm, 16);
            sm += __shfl_xor(sm, 32);
            hid[q] = sm;
        }
        float po = b2s;
#pragma unroll
        for (int q = 0; q < 16; ++q)
            po = fmaf(fmaxf(hid[q] + b1s[q], 0.f), w2s[q], po);
        if (g == 0) out[blockBase + s * 64 + n0] = po;
    }
}

extern "C" void kernel_launch(void* const* d_in, const int* in_sizes, int n_in,
                              void* d_out, int out_size, void* d_ws, size_t ws_size,
                              hipStream_t stream) {
    (void)in_sizes; (void)n_in; (void)d_ws; (void)ws_size; (void)out_size;
    const float* x    = (const float*)d_in[0];
    const float* w_ih = (const float*)d_in[1];
    const float* w_hh = (const float*)d_in[2];
    const float* b_ih = (const float*)d_in[3];
    const float* b_hh = (const float*)d_in[4];
    const float* w1   = (const float*)d_in[5];
    const float* b1   = (const float*)d_in[6];
    const float* w2   = (const float*)d_in[7];
    const float* b2   = (const float*)d_in[8];
    float* outp = (float*)d_out;

    dim3 grid(131072 / 256);   // 256 batch rows per block (4 waves x 16 x 4 streams)
    dim3 block(256);
    hipLaunchKernelGGL(lstm_fused, grid, block, 0, stream,
                       x, w_ih, w_hh, b_ih, b_hh, w1, b1, w2, b2, outp);
}

// Round 8
// 95.601 us; speedup vs baseline: 1.4548x; 1.0562x over previous
//
#include <hip/hip_runtime.h>

// LSTM (B=131072, T=24, input=3, H=32) + Linear(32,16)+ReLU+Linear(16,1)
//
// gates^T = Whh * h^T (mfma 16x16x32 f16) + Wib * [x;1]^T (mfma 16x16x16 f16).
// Two independent batch streams per wave share one VGPR-resident weight set.
// R7 lesson: the compiler serialized the streams (VGPR=72!) killing ILP. This
// version FORCES interleaving structurally: Phase A issues ALL 32 MFMAs into
// a live acc[2][2][4] array; Phase B runs activations as stage-parallel loops
// over the 8 independent unit-pair chains (all exp2 of a stage together, then
// all rcp, ...), so trans/VALU latency is covered by sibling chains in-wave.
// Unit->row permutation keeps h lane-local (zero cross-lane traffic, no
// per-step barrier). Weights prescaled by log2e (2*log2e for g); c-state in
// 2*log2e domain so ez=exp2(cs). FP16 storage for h/w/x (R5 lesson).

typedef _Float16 f16x8 __attribute__((ext_vector_type(8)));
typedef _Float16 f16x4 __attribute__((ext_vector_type(4)));
typedef _Float16 f16x2 __attribute__((ext_vector_type(2)));
typedef float f32x4 __attribute__((ext_vector_type(4)));
typedef float f32x2 __attribute__((ext_vector_type(2)));

#define L2E 1.4426950408889634f

#if __has_builtin(__builtin_amdgcn_mfma_f32_16x16x16f16)
#define HAVE_MFMA16 1
#else
#define HAVE_MFMA16 0
#endif

__device__ __forceinline__ float fexp2(float v) { return __builtin_amdgcn_exp2f(v); }
__device__ __forceinline__ float frcp(float v)  { return __builtin_amdgcn_rcpf(v); }

__global__ __launch_bounds__(256, 2)
void lstm_fused(const float* __restrict__ x,
                const float* __restrict__ w_ih,
                const float* __restrict__ w_hh,
                const float* __restrict__ b_ih,
                const float* __restrict__ b_hh,
                const float* __restrict__ w1,
                const float* __restrict__ b1,
                const float* __restrict__ w2,
                const float* __restrict__ b2,
                float* __restrict__ out)
{
    __shared__ int2  xq[24 * 128];  // [t][n] packed f16 {x0,x1,x2,1.0} (24 KB)
    __shared__ float w1s[512];
    __shared__ float b1s[16];
    __shared__ float w2s[16];
    __shared__ float b2s;

    const int tid  = threadIdx.x;
    const int lane = tid & 63;
    const int wv   = tid >> 6;      // wave id 0..3
    const int c    = lane & 15;     // batch column within wave tile
    const int g    = lane >> 4;     // k-group 0..3
    const int blockBase = blockIdx.x * 128;

    for (int i = tid; i < 512; i += 256) w1s[i] = w1[i];
    if (tid < 16) { b1s[tid] = b1[tid]; w2s[tid] = w2[tid]; }
    if (tid == 16) b2s = b2[0];

    // ---- stage x: pack (x0,x1,x2,1.0) as f16 per (row, t) ----
    for (int it = 0; it < 12; ++it) {
        int p = tid + it * 256;          // 0..3071 = 128 rows * 24 steps
        int n = p / 24;
        int t = p - n * 24;
        const float* xp = x + ((blockBase + n) * 24 + t) * 3;
        union { f16x4 h; int2 i2; } tq;
        tq.h[0] = (_Float16)xp[0];
        tq.h[1] = (_Float16)xp[1];
        tq.h[2] = (_Float16)xp[2];
        tq.h[3] = (_Float16)1.0f;        // hits fused-bias column
        xq[t * 128 + n] = tq.i2;
    }

    // ---- preload weight A-frags (wave-uniform, permuted rows, prescaled) ----
    // MFMA (G,p) row r computes unit(r,p) = 8*(r>>2) + 4p + (r&3).
    // whh element e = W[row=c][k = 8g+e]; wib element e = k = 4g+e (K=16 frag).
    f16x8 whh[8];
#if HAVE_MFMA16
    f16x4 wib[8];
#else
    f16x8 wib[8];
#endif
    const int ubase = 8 * (c >> 2) + (c & 3);
#pragma unroll
    for (int G = 0; G < 4; ++G) {
        const float scale = (G == 2) ? (2.f * L2E) : L2E;
#pragma unroll
        for (int p = 0; p < 2; ++p) {
            const int row = G * 32 + ubase + 4 * p;
            const float* wr = w_hh + row * 32 + g * 8;
            f16x8 a;
#pragma unroll
            for (int e = 0; e < 8; ++e) a[e] = (_Float16)(wr[e] * scale);
            whh[G * 2 + p] = a;
            _Float16 c0 = 0, c1 = 0, c2 = 0, c3 = 0;
            if (g == 0) {
                c0 = (_Float16)(w_ih[row * 3 + 0] * scale);
                c1 = (_Float16)(w_ih[row * 3 + 1] * scale);
                c2 = (_Float16)(w_ih[row * 3 + 2] * scale);
                c3 = (_Float16)((b_ih[row] + b_hh[row]) * scale);
            }
#if HAVE_MFMA16
            f16x4 bb = {c0, c1, c2, c3};
#else
            f16x8 bb = {c0, c1, c2, c3, 0, 0, 0, 0};
#endif
            wib[G * 2 + p] = bb;
        }
    }

    __syncthreads();   // xq/w1s staged (only barrier in the kernel)

    // ---- two independent batch streams per wave ----
    f32x2 cz = {0.f, 0.f};
    f32x2 cst2[8];                        // [q = s*4 + p*2 + j]
#pragma unroll
    for (int q = 0; q < 8; ++q) cst2[q] = cz;
    union hu_t { f16x2 p2[4]; f16x8 v; int4 i4; } hreg[2];
    hreg[0].i4 = make_int4(0, 0, 0, 0);
    hreg[1].i4 = make_int4(0, 0, 0, 0);

    const int n0 = wv * 16 + c;          // stream 0 column; stream 1: +64
    int2 xv[2];
    xv[0] = xq[n0];
    xv[1] = xq[n0 + 64];

#pragma unroll 1
    for (int t = 0; t < 24; ++t) {
        const int tn = (t < 23) ? t + 1 : 23;
        int2 xn0 = xq[tn * 128 + n0];        // prefetch next step
        int2 xn1 = xq[tn * 128 + n0 + 64];

        // ================= Phase A: ALL MFMAs, both streams =================
        f32x4 acc[2][2][4];                  // [s][p][gate] — all live at once
        const f32x4 z = {0.f, 0.f, 0.f, 0.f};
#pragma unroll
        for (int s = 0; s < 2; ++s) {
            f16x8 hf = hreg[s].v;
#pragma unroll
            for (int p = 0; p < 2; ++p) {
#pragma unroll
                for (int G = 0; G < 4; ++G)
                    acc[s][p][G] = __builtin_amdgcn_mfma_f32_16x16x32_f16(
                        whh[2 * G + p], hf, z, 0, 0, 0);
            }
        }
#pragma unroll
        for (int s = 0; s < 2; ++s) {
            int xlo = (g == 0) ? xv[s].x : 0;
            int xhi = (g == 0) ? xv[s].y : 0;
#if HAVE_MFMA16
            union { int2 i2; f16x4 v; } xu;
            xu.i2 = make_int2(xlo, xhi);
            f16x4 xf = xu.v;
#else
            union { int4 i4; f16x8 v; } xu;
            xu.i4 = make_int4(xlo, xhi, 0, 0);
            f16x8 xf = xu.v;
#endif
#pragma unroll
            for (int p = 0; p < 2; ++p) {
#pragma unroll
                for (int G = 0; G < 4; ++G)
#if HAVE_MFMA16
                    acc[s][p][G] = __builtin_amdgcn_mfma_f32_16x16x16f16(
                        wib[2 * G + p], xf, acc[s][p][G], 0, 0, 0);
#else
                    acc[s][p][G] = __builtin_amdgcn_mfma_f32_16x16x32_f16(
                        wib[2 * G + p], xf, acc[s][p][G], 0, 0, 0);
#endif
            }
        }

        // ====== Phase B: stage-parallel activation over 8 pair-chains ======
        // q = s*4 + p*2 + j ; pair j covers acc elements {2j, 2j+1}
        f32x2 vi[8], vf[8], vg[8], vo[8];
#pragma unroll
        for (int q = 0; q < 8; ++q) {
            const int s = q >> 2, p = (q >> 1) & 1, j = q & 1;
            vi[q][0] = acc[s][p][0][2 * j]; vi[q][1] = acc[s][p][0][2 * j + 1];
            vf[q][0] = acc[s][p][1][2 * j]; vf[q][1] = acc[s][p][1][2 * j + 1];
            vg[q][0] = acc[s][p][2][2 * j]; vg[q][1] = acc[s][p][2][2 * j + 1];
            vo[q][0] = acc[s][p][3][2 * j]; vo[q][1] = acc[s][p][3][2 * j + 1];
        }
        f32x2 ex[8], ey[8], ef[8];
#pragma unroll
        for (int q = 0; q < 8; ++q) {        // stage 1: independent exp2s
            ex[q][0] = fexp2(-vi[q][0]); ex[q][1] = fexp2(-vi[q][1]);
            ey[q][0] = fexp2(vg[q][0]);  ey[q][1] = fexp2(vg[q][1]);
            ef[q][0] = fexp2(-vf[q][0]); ef[q][1] = fexp2(-vf[q][1]);
        }
        const f32x2 one = {1.f, 1.f};
        const f32x2 K2  = {2.f * L2E, 2.f * L2E};
        f32x2 axy[8], efp[8], r1[8];
#pragma unroll
        for (int q = 0; q < 8; ++q) {        // stage 2: denominators + rcp
            axy[q] = (one + ex[q]) * (one + ey[q]);
            efp[q] = one + ef[q];
            f32x2 dd = axy[q] * efp[q];
            r1[q][0] = frcp(dd[0]); r1[q][1] = frcp(dd[1]);
        }
        f32x2 ez[8], ew[8];
#pragma unroll
        for (int q = 0; q < 8; ++q) {        // stage 3: c update + exp2s
            f32x2 igs = (ey[q] * K2 - K2) * efp[q] * r1[q];
            f32x2 fs  = axy[q] * r1[q];
            cst2[q] = fs * cst2[q] + igs;
            ew[q][0] = fexp2(-vo[q][0]); ew[q][1] = fexp2(-vo[q][1]);
            ez[q][0] = fexp2(cst2[q][0]); ez[q][1] = fexp2(cst2[q][1]);
        }
#pragma unroll
        for (int q = 0; q < 8; ++q) {        // stage 4: h = sig(o)*tanh(c)
            const int s = q >> 2, p = (q >> 1) & 1, j = q & 1;
            f32x2 d2 = (one + ew[q]) * (one + ez[q]);
            f32x2 r2; r2[0] = frcp(d2[0]); r2[1] = frcp(d2[1]);
            f32x2 hn = (ez[q] - one) * r2;
            f16x2 hh; hh[0] = (_Float16)hn[0]; hh[1] = (_Float16)hn[1];
            hreg[s].p2[2 * p + j] = hh;
        }
        xv[0] = xn0;
        xv[1] = xn1;
    }

    // ---- head: lane (c,g) holds h[8g..8g+7] of batch cols n0, n0+64 ----
#pragma unroll
    for (int s = 0; s < 2; ++s) {
        float hfin[8];
#pragma unroll
        for (int d = 0; d < 8; ++d) hfin[d] = (float)hreg[s].v[d];
        float hid[16];
#pragma unroll
        for (int q = 0; q < 16; ++q) {
            const float4* wrow = (const float4*)(w1s + q * 32 + g * 8);
            float4 wa = wrow[0], wb = wrow[1];
            float sm = wa.x * hfin[0] + wa.y * hfin[1] + wa.z * hfin[2] + wa.w * hfin[3]
                     + wb.x * hfin[4] + wb.y * hfin[5] + wb.z * hfin[6] + wb.w * hfin[7];
            sm += __shfl_xor(sm, 16);
            sm += __shfl_xor(sm, 32);
            hid[q] = sm;
        }
        float po = b2s;
#pragma unroll
        for (int q = 0; q < 16; ++q)
            po = fmaf(fmaxf(hid[q] + b1s[q], 0.f), w2s[q], po);
        if (g == 0) out[blockBase + s * 64 + n0] = po;
    }
}

extern "C" void kernel_launch(void* const* d_in, const int* in_sizes, int n_in,
                              void* d_out, int out_size, void* d_ws, size_t ws_size,
                              hipStream_t stream) {
    (void)in_sizes; (void)n_in; (void)d_ws; (void)ws_size; (void)out_size;
    const float* x    = (const float*)d_in[0];
    const float* w_ih = (const float*)d_in[1];
    const float* w_hh = (const float*)d_in[2];
    const float* b_ih = (const float*)d_in[3];
    const float* b_hh = (const float*)d_in[4];
    const float* w1   = (const float*)d_in[5];
    const float* b1   = (const float*)d_in[6];
    const float* w2   = (const float*)d_in[7];
    const float* b2   = (const float*)d_in[8];
    float* outp = (float*)d_out;

    dim3 grid(131072 / 128);   // 128 batch rows per block (4 waves x 16 x 2 streams)
    dim3 block(256);
    hipLaunchKernelGGL(lstm_fused, grid, block, 0, stream,
                       x, w_ih, w_hh, b_ih, b_hh, w1, b1, w2, b2, outp);
}